// Round 2
// baseline (34606.927 us; speedup 1.0000x reference)
//
#include <hip/hip_runtime.h>
#include <cstdint>

#define BATCH 4096
#define LATENT 128
#define RNN 512
#define CODE 512
#define DISC 64
#define NSEG 64
#define UNPACK_COLS 130  // LATENT + INPUT

// ------------- threefry2x32, JAX partitionable mode, key = (0, 42) -----------
// bits(n) = w0 ^ w1 where (w0,w1) = threefry2x32(key=(0,42), counter=(0, n)).
__device__ __forceinline__ uint32_t rotl32(uint32_t x, uint32_t r) {
  return (x << r) | (x >> (32u - r));
}

__device__ __forceinline__ uint32_t threefry_bits(uint32_t n) {
  const uint32_t k0 = 0u, k1 = 42u;
  const uint32_t ks2 = k0 ^ k1 ^ 0x1BD11BDAu;
  uint32_t x0 = 0u, x1 = n;          // counter = (hi32, lo32) of flat index
  x0 += k0; x1 += k1;
#define TF_ROUND(r) { x0 += x1; x1 = rotl32(x1, r); x1 ^= x0; }
  TF_ROUND(13) TF_ROUND(15) TF_ROUND(26) TF_ROUND(6)
  x0 += k1;  x1 += ks2 + 1u;
  TF_ROUND(17) TF_ROUND(29) TF_ROUND(16) TF_ROUND(24)
  x0 += ks2; x1 += k0 + 2u;
  TF_ROUND(13) TF_ROUND(15) TF_ROUND(26) TF_ROUND(6)
  x0 += k0;  x1 += k1 + 3u;
  TF_ROUND(17) TF_ROUND(29) TF_ROUND(16) TF_ROUND(24)
  x0 += k1;  x1 += ks2 + 4u;
  TF_ROUND(13) TF_ROUND(15) TF_ROUND(26) TF_ROUND(6)
  x0 += ks2; x1 += k0 + 5u;
#undef TF_ROUND
  return x0 ^ x1;
}

// ---------------- base = latent @ W_unpack[:, :128]^T + b_unpack --------------
__global__ __launch_bounds__(256) void base_kernel(
    const float* __restrict__ latent, const float* __restrict__ Wu,
    const float* __restrict__ bu, float* __restrict__ base) {
  __shared__ float lrow[LATENT];
  const int b = blockIdx.x;
  if (threadIdx.x < LATENT) lrow[threadIdx.x] = latent[b * LATENT + threadIdx.x];
  __syncthreads();
  for (int n = threadIdx.x; n < CODE; n += 256) {
    const float* wr = Wu + (size_t)n * UNPACK_COLS;
    float acc = 0.f;
#pragma unroll 8
    for (int k = 0; k < LATENT; ++k) acc += lrow[k] * wr[k];
    base[(size_t)b * CODE + n] = acc + bu[n];
  }
}

// ---------------- x = tanh(base + angle * W_unpack[:, 128]) -------------------
__global__ __launch_bounds__(256) void x_kernel(
    const float* __restrict__ base, const float* __restrict__ angle,
    const float* __restrict__ Wu, float* __restrict__ xo) {
  const int idx = blockIdx.x * 256 + threadIdx.x;
  const int b = idx >> 9;
  const int n = idx & 511;
  xo[idx] = tanhf(base[idx] + angle[b] * Wu[(size_t)n * UNPACK_COLS + 128]);
}

// ------------- gates = A1@W1^T + A2@W2^T + b1 + b2  (M=4096,N=2048,K=512) -----
#define BM 128
#define BN 128
#define BK 16

__global__ __launch_bounds__(256) void gemm_dual(
    const float* __restrict__ A1, const float* __restrict__ W1,
    const float* __restrict__ A2, const float* __restrict__ W2,
    const float* __restrict__ b1, const float* __restrict__ b2,
    float* __restrict__ C) {
  const int K = RNN;        // 512 per segment
  const int N = 4 * RNN;    // 2048
  __shared__ __align__(16) float As[BK][BM];
  __shared__ __align__(16) float Ws[BK][BN];
  const int tid = threadIdx.x;
  const int tx = tid & 15, ty = tid >> 4;
  const int rowBase = blockIdx.y * BM;
  const int colBase = blockIdx.x * BN;
  const int lrow = tid >> 2;        // 0..63
  const int lk = (tid & 3) * 4;     // 0,4,8,12

  float acc[8][8];
#pragma unroll
  for (int i = 0; i < 8; ++i)
#pragma unroll
    for (int j = 0; j < 8; ++j) acc[i][j] = 0.f;

  for (int seg = 0; seg < 2; ++seg) {
    const float* __restrict__ A = seg ? A2 : A1;
    const float* __restrict__ W = seg ? W2 : W1;
    for (int k0 = 0; k0 < K; k0 += BK) {
      __syncthreads();
#pragma unroll
      for (int r = 0; r < 2; ++r) {
        const int rr = lrow + r * 64;
        float4 va = *(const float4*)&A[(size_t)(rowBase + rr) * K + k0 + lk];
        As[lk + 0][rr] = va.x; As[lk + 1][rr] = va.y;
        As[lk + 2][rr] = va.z; As[lk + 3][rr] = va.w;
        float4 vw = *(const float4*)&W[(size_t)(colBase + rr) * K + k0 + lk];
        Ws[lk + 0][rr] = vw.x; Ws[lk + 1][rr] = vw.y;
        Ws[lk + 2][rr] = vw.z; Ws[lk + 3][rr] = vw.w;
      }
      __syncthreads();
#pragma unroll
      for (int kk = 0; kk < BK; ++kk) {
        float4 a0 = *(const float4*)&As[kk][ty * 8];
        float4 a1 = *(const float4*)&As[kk][ty * 8 + 4];
        float4 w0 = *(const float4*)&Ws[kk][tx * 8];
        float4 w1 = *(const float4*)&Ws[kk][tx * 8 + 4];
        float av[8] = {a0.x, a0.y, a0.z, a0.w, a1.x, a1.y, a1.z, a1.w};
        float wv[8] = {w0.x, w0.y, w0.z, w0.w, w1.x, w1.y, w1.z, w1.w};
#pragma unroll
        for (int i = 0; i < 8; ++i)
#pragma unroll
          for (int j = 0; j < 8; ++j) acc[i][j] += av[i] * wv[j];
      }
    }
  }
  // epilogue: add biases, store
#pragma unroll
  for (int i = 0; i < 8; ++i) {
    const int row = rowBase + ty * 8 + i;
#pragma unroll
    for (int j4 = 0; j4 < 2; ++j4) {
      const int col = colBase + tx * 8 + j4 * 4;
      float4 o;
      o.x = acc[i][j4 * 4 + 0] + b1[col + 0] + b2[col + 0];
      o.y = acc[i][j4 * 4 + 1] + b1[col + 1] + b2[col + 1];
      o.z = acc[i][j4 * 4 + 2] + b1[col + 2] + b2[col + 2];
      o.w = acc[i][j4 * 4 + 3] + b1[col + 3] + b2[col + 3];
      *(float4*)&C[(size_t)row * N + col] = o;
    }
  }
}

// ---------------- LSTM pointwise: (i,f,g,o) gate order ------------------------
__device__ __forceinline__ float sigmoidf_(float v) {
  return 1.0f / (1.0f + expf(-v));
}

__global__ __launch_bounds__(256) void lstm_kernel(
    const float* __restrict__ gates, float* __restrict__ h, float* __restrict__ c) {
  const int idx = blockIdx.x * 256 + threadIdx.x;  // 0 .. B*RNN
  const int b = idx >> 9;
  const int j = idx & 511;
  const float* g = gates + (size_t)b * (4 * RNN);
  const float gi = g[j];
  const float gf = g[RNN + j];
  const float gg = g[2 * RNN + j];
  const float go = g[3 * RNN + j];
  const float cn = sigmoidf_(gf) * c[idx] + sigmoidf_(gi) * tanhf(gg);
  c[idx] = cn;
  h[idx] = sigmoidf_(go) * tanhf(cn);
}

// -------- head: logits -> +gumbel -> softmax -> hard argmax -> angle ----------
__global__ __launch_bounds__(64) void head_kernel(
    const float* __restrict__ h1, const float* __restrict__ Wang,
    const float* __restrict__ bang, float* __restrict__ angle,
    float* __restrict__ out, int s) {
  const int b = blockIdx.x;
  const int d = threadIdx.x;
  const float4* hr = (const float4*)(h1 + (size_t)b * RNN);
  const float4* wr = (const float4*)(Wang + (size_t)d * RNN);
  float acc = 0.f;
#pragma unroll 16
  for (int k = 0; k < RNN / 4; ++k) {
    float4 a = hr[k], w = wr[k];
    acc += a.x * w.x; acc += a.y * w.y; acc += a.z * w.z; acc += a.w * w.w;
  }
  float z = acc + bang[d];
  // gumbel noise, bit-exact u (JAX partitionable threefry)
  const uint32_t n = ((uint32_t)s * BATCH + (uint32_t)b) * DISC + (uint32_t)d;
  const uint32_t bits = threefry_bits(n);
  const float f = __uint_as_float((bits >> 9) | 0x3f800000u) - 1.0f;
  const float u = fmaxf(1e-8f, f + 1e-8f);
  const float gum = -logf(-logf(u));
  z += gum;
  // softmax (mimic reference: max, exp, sum, divide), then first-index argmax
  float m = z;
#pragma unroll
  for (int off = 32; off; off >>= 1) m = fmaxf(m, __shfl_xor(m, off));
  const float e = expf(z - m);
  float ssum = e;
#pragma unroll
  for (int off = 32; off; off >>= 1) ssum += __shfl_xor(ssum, off);
  const float y = e / ssum;
  float ymax = y;
#pragma unroll
  for (int off = 32; off; off >>= 1) ymax = fmaxf(ymax, __shfl_xor(ymax, off));
  const unsigned long long mask = __ballot(y == ymax);
  const int k = __ffsll(mask) - 1;
  if (d == 0) {
    const float sp = -1.0f + (2.0f / 63.0f) * (float)k;  // linspace(-1,1,64)[k]
    angle[b] = sp;
    out[((size_t)b * NSEG + s) * 2 + 0] = sp;
    out[((size_t)b * NSEG + s) * 2 + 1] = 0.0f;
  }
}

// ------------------------------- launch ---------------------------------------
extern "C" void kernel_launch(void* const* d_in, const int* in_sizes, int n_in,
                              void* d_out, int out_size, void* d_ws, size_t ws_size,
                              hipStream_t stream) {
  const float* latent   = (const float*)d_in[0];
  const float* W_unpack = (const float*)d_in[1];
  const float* b_unpack = (const float*)d_in[2];
  const float* Wih0     = (const float*)d_in[3];
  const float* Whh0     = (const float*)d_in[4];
  const float* bih0     = (const float*)d_in[5];
  const float* bhh0     = (const float*)d_in[6];
  const float* Wih1     = (const float*)d_in[7];
  const float* Whh1     = (const float*)d_in[8];
  const float* bih1     = (const float*)d_in[9];
  const float* bhh1     = (const float*)d_in[10];
  const float* W_angle  = (const float*)d_in[11];
  const float* b_angle  = (const float*)d_in[12];
  float* out = (float*)d_out;

  float* ws    = (float*)d_ws;
  float* h0    = ws;
  float* c0    = h0 + (size_t)BATCH * RNN;
  float* h1    = c0 + (size_t)BATCH * RNN;
  float* c1    = h1 + (size_t)BATCH * RNN;
  float* angle = c1 + (size_t)BATCH * RNN;
  float* base  = angle + BATCH;
  float* x     = base + (size_t)BATCH * CODE;
  float* gates = x + (size_t)BATCH * CODE;

  // zero h0,c0,h1,c1,angle (must re-init every call: harness replays the graph)
  hipMemsetAsync(ws, 0, ((size_t)4 * BATCH * RNN + BATCH) * sizeof(float), stream);

  base_kernel<<<BATCH, 256, 0, stream>>>(latent, W_unpack, b_unpack, base);

  dim3 ggrid((4 * RNN) / BN, BATCH / BM);  // (16, 32)
  for (int s = 0; s < NSEG; ++s) {
    x_kernel<<<(BATCH * CODE) / 256, 256, 0, stream>>>(base, angle, W_unpack, x);
    gemm_dual<<<ggrid, 256, 0, stream>>>(x, Wih0, h0, Whh0, bih0, bhh0, gates);
    lstm_kernel<<<(BATCH * RNN) / 256, 256, 0, stream>>>(gates, h0, c0);
    gemm_dual<<<ggrid, 256, 0, stream>>>(h0, Wih1, h1, Whh1, bih1, bhh1, gates);
    lstm_kernel<<<(BATCH * RNN) / 256, 256, 0, stream>>>(gates, h1, c1);
    head_kernel<<<BATCH, 64, 0, stream>>>(h1, W_angle, b_angle, angle, out, s);
  }
}

// Round 3
// 33792.303 us; speedup vs baseline: 1.0241x; 1.0241x over previous
//
#include <hip/hip_runtime.h>
#include <cstdint>

#define BATCH 4096
#define LATENT 128
#define RNN 512
#define CODE 512
#define DISC 64
#define NSEG 64
#define UNPACK_COLS 130  // LATENT + INPUT

// ------------- threefry2x32, JAX partitionable mode, key = (0, 42) -----------
// bits(n) = w0 ^ w1 where (w0,w1) = threefry2x32(key=(0,42), counter=(0, n)).
__device__ __forceinline__ uint32_t rotl32(uint32_t x, uint32_t r) {
  return (x << r) | (x >> (32u - r));
}

__device__ __forceinline__ uint32_t threefry_bits(uint32_t n) {
  const uint32_t k0 = 0u, k1 = 42u;
  const uint32_t ks2 = k0 ^ k1 ^ 0x1BD11BDAu;
  uint32_t x0 = 0u, x1 = n;          // counter = (hi32, lo32) of flat index
  x0 += k0; x1 += k1;
#define TF_ROUND(r) { x0 += x1; x1 = rotl32(x1, r); x1 ^= x0; }
  TF_ROUND(13) TF_ROUND(15) TF_ROUND(26) TF_ROUND(6)
  x0 += k1;  x1 += ks2 + 1u;
  TF_ROUND(17) TF_ROUND(29) TF_ROUND(16) TF_ROUND(24)
  x0 += ks2; x1 += k0 + 2u;
  TF_ROUND(13) TF_ROUND(15) TF_ROUND(26) TF_ROUND(6)
  x0 += k0;  x1 += k1 + 3u;
  TF_ROUND(17) TF_ROUND(29) TF_ROUND(16) TF_ROUND(24)
  x0 += k1;  x1 += ks2 + 4u;
  TF_ROUND(13) TF_ROUND(15) TF_ROUND(26) TF_ROUND(6)
  x0 += ks2; x1 += k0 + 5u;
#undef TF_ROUND
  return x0 ^ x1;
}

__device__ __forceinline__ float sigmoidf_(float v) {
  return 1.0f / (1.0f + expf(-v));
}

// ---------------- base = latent @ W_unpack[:, :128]^T + b_unpack --------------
__global__ __launch_bounds__(256) void base_kernel(
    const float* __restrict__ latent, const float* __restrict__ Wu,
    const float* __restrict__ bu, float* __restrict__ base) {
  __shared__ float lrow[LATENT];
  const int b = blockIdx.x;
  if (threadIdx.x < LATENT) lrow[threadIdx.x] = latent[b * LATENT + threadIdx.x];
  __syncthreads();
  for (int n = threadIdx.x; n < CODE; n += 256) {
    const float* wr = Wu + (size_t)n * UNPACK_COLS;
    float acc = 0.f;
#pragma unroll 8
    for (int k = 0; k < LATENT; ++k) acc += lrow[k] * wr[k];
    base[(size_t)b * CODE + n] = acc + bu[n];
  }
}

// ---------------- x = tanh(base + angle * W_unpack[:, 128]) -------------------
__global__ __launch_bounds__(256) void x_kernel(
    const float* __restrict__ base, const float* __restrict__ angle,
    const float* __restrict__ Wu, float* __restrict__ xo) {
  const int idx = blockIdx.x * 256 + threadIdx.x;
  const int b = idx >> 9;
  const int n = idx & 511;
  xo[idx] = tanhf(base[idx] + angle[b] * Wu[(size_t)n * UNPACK_COLS + 128]);
}

// ----- fused: gates = A1@W1^T + A2@W2^T + b1 + b2 ; (h,c) = LSTM(gates, c) ----
// Tile: BM=128 rows x BN=128 "cols" where tile col t maps to gate (t>>5) and
// rnn-col bx*32 + (t&31).  K-major LDS with XOR swizzle col ^ ((row>>2&3)<<3):
// staging stores and fragment reads both conflict-free (<=2-way).
#define BM 128
#define BN 128
#define BK 16

__global__ __launch_bounds__(256) void gemm_lstm(
    const float* __restrict__ A1, const float* __restrict__ W1,
    const float* __restrict__ A2, const float* __restrict__ W2,
    const float* __restrict__ b1, const float* __restrict__ b2,
    float* __restrict__ c_io, float* __restrict__ h_out) {
  const int K = RNN;
  __shared__ __align__(16) float As[BK][BM];
  __shared__ __align__(16) float Ws[BK][BN];
  const int tid = threadIdx.x;
  const int tx = tid & 15, ty = tid >> 4;
  const int bx = blockIdx.x;            // 16 N-tiles of (4 gates x 32 cols)
  const int rowBase = blockIdx.y * BM;
  const int lrow = tid >> 2;            // 0..63
  const int lk = (tid & 3) * 4;         // k sub-offset 0,4,8,12
  const int swz = (tid & 3) << 3;       // swizzle for stored rows lk..lk+3

  float acc[8][8];
#pragma unroll
  for (int i = 0; i < 8; ++i)
#pragma unroll
    for (int j = 0; j < 8; ++j) acc[i][j] = 0.f;

  for (int seg = 0; seg < 2; ++seg) {
    const float* __restrict__ A = seg ? A2 : A1;
    const float* __restrict__ W = seg ? W2 : W1;
    for (int k0 = 0; k0 < K; k0 += BK) {
      __syncthreads();
#pragma unroll
      for (int r = 0; r < 2; ++r) {
        const int rr = lrow + r * 64;
        const int cc = rr ^ swz;
        const float4 va = *(const float4*)&A[(size_t)(rowBase + rr) * K + k0 + lk];
        As[lk + 0][cc] = va.x; As[lk + 1][cc] = va.y;
        As[lk + 2][cc] = va.z; As[lk + 3][cc] = va.w;
        const int wn = ((rr >> 5) * RNN) + (bx << 5) + (rr & 31);
        const float4 vw = *(const float4*)&W[(size_t)wn * K + k0 + lk];
        Ws[lk + 0][cc] = vw.x; Ws[lk + 1][cc] = vw.y;
        Ws[lk + 2][cc] = vw.z; Ws[lk + 3][cc] = vw.w;
      }
      __syncthreads();
#pragma unroll
      for (int kk = 0; kk < BK; ++kk) {
        const int swk = (kk & 12) << 1;  // ((kk>>2)&3)<<3
        const float4 a0 = *(const float4*)&As[kk][(ty * 4) ^ swk];
        const float4 a1 = *(const float4*)&As[kk][(64 + ty * 4) ^ swk];
        const float4 w0 = *(const float4*)&Ws[kk][(tx * 4) ^ swk];
        const float4 w1 = *(const float4*)&Ws[kk][(64 + tx * 4) ^ swk];
        const float av[8] = {a0.x, a0.y, a0.z, a0.w, a1.x, a1.y, a1.z, a1.w};
        const float wv[8] = {w0.x, w0.y, w0.z, w0.w, w1.x, w1.y, w1.z, w1.w};
#pragma unroll
        for (int i = 0; i < 8; ++i)
#pragma unroll
          for (int j = 0; j < 8; ++j) acc[i][j] += av[i] * wv[j];
      }
    }
  }

  // ---- fused LSTM epilogue ----
  // Thread cols: group0 = tile cols tx*4..+3 (gate 0 if tx<8 else 1),
  //              group1 = tile cols 64+tx*4..+3 (gate 2 if tx<8 else 3).
  // Lane pair (tx, tx^8) shares rnn-cols jl=(tx&7)*4..+3: one holds (i,g),
  // the other (f,o).  Exchange via shfl_xor(8); tx<8 lanes finish rows 0..63,
  // tx>=8 lanes rows 64..127.
  const int myjl = (tx & 7) * 4;
  const int jbase = (bx << 5) + myjl;       // rnn col 0..508
  const int g0 = (tx < 8) ? 0 : 1;
  const int g1 = g0 + 2;
  float bs0[4], bs1[4];
#pragma unroll
  for (int j = 0; j < 4; ++j) {
    bs0[j] = b1[g0 * RNN + jbase + j] + b2[g0 * RNN + jbase + j];
    bs1[j] = b1[g1 * RNN + jbase + j] + b2[g1 * RNN + jbase + j];
  }
  const bool low = (tx < 8);
#pragma unroll
  for (int i = 0; i < 8; ++i) {
    float v0[4], v1[4], p0[4], p1[4];
#pragma unroll
    for (int j = 0; j < 4; ++j) {
      v0[j] = acc[i][j] + bs0[j];
      v1[j] = acc[i][4 + j] + bs1[j];
      p0[j] = __shfl_xor(v0[j], 8);
      p1[j] = __shfl_xor(v1[j], 8);
    }
    const bool mine = low ? (i < 4) : (i >= 4);
    if (mine) {
      const int row = rowBase + (low ? (ty * 4 + i) : (64 + ty * 4 + (i - 4)));
      const size_t off = (size_t)row * RNN + jbase;
      const float4 cold = *(const float4*)&c_io[off];
      const float co[4] = {cold.x, cold.y, cold.z, cold.w};
      float cn[4], hn[4];
#pragma unroll
      for (int j = 0; j < 4; ++j) {
        const float fi = low ? v0[j] : p0[j];
        const float fg = low ? v1[j] : p1[j];
        const float ff = low ? p0[j] : v0[j];
        const float fo = low ? p1[j] : v1[j];
        const float c2 = sigmoidf_(ff) * co[j] + sigmoidf_(fi) * tanhf(fg);
        cn[j] = c2;
        hn[j] = sigmoidf_(fo) * tanhf(c2);
      }
      *(float4*)&c_io[off] = make_float4(cn[0], cn[1], cn[2], cn[3]);
      *(float4*)&h_out[off] = make_float4(hn[0], hn[1], hn[2], hn[3]);
    }
  }
}

// -------- head: logits -> +gumbel -> softmax -> hard argmax -> angle ----------
__global__ __launch_bounds__(64) void head_kernel(
    const float* __restrict__ h1, const float* __restrict__ Wang,
    const float* __restrict__ bang, float* __restrict__ angle,
    float* __restrict__ out, int s) {
  const int b = blockIdx.x;
  const int d = threadIdx.x;
  const float4* hr = (const float4*)(h1 + (size_t)b * RNN);
  const float4* wr = (const float4*)(Wang + (size_t)d * RNN);
  float acc = 0.f;
#pragma unroll 16
  for (int k = 0; k < RNN / 4; ++k) {
    float4 a = hr[k], w = wr[k];
    acc += a.x * w.x; acc += a.y * w.y; acc += a.z * w.z; acc += a.w * w.w;
  }
  float z = acc + bang[d];
  const uint32_t n = ((uint32_t)s * BATCH + (uint32_t)b) * DISC + (uint32_t)d;
  const uint32_t bits = threefry_bits(n);
  const float f = __uint_as_float((bits >> 9) | 0x3f800000u) - 1.0f;
  const float u = fmaxf(1e-8f, f + 1e-8f);
  const float gum = -logf(-logf(u));
  z += gum;
  float m = z;
#pragma unroll
  for (int off = 32; off; off >>= 1) m = fmaxf(m, __shfl_xor(m, off));
  const float e = expf(z - m);
  float ssum = e;
#pragma unroll
  for (int off = 32; off; off >>= 1) ssum += __shfl_xor(ssum, off);
  const float y = e / ssum;
  float ymax = y;
#pragma unroll
  for (int off = 32; off; off >>= 1) ymax = fmaxf(ymax, __shfl_xor(ymax, off));
  const unsigned long long mask = __ballot(y == ymax);
  const int k = __ffsll(mask) - 1;
  if (d == 0) {
    const float sp = -1.0f + (2.0f / 63.0f) * (float)k;  // linspace(-1,1,64)[k]
    angle[b] = sp;
    out[((size_t)b * NSEG + s) * 2 + 0] = sp;
    out[((size_t)b * NSEG + s) * 2 + 1] = 0.0f;
  }
}

// ------------------------------- launch ---------------------------------------
extern "C" void kernel_launch(void* const* d_in, const int* in_sizes, int n_in,
                              void* d_out, int out_size, void* d_ws, size_t ws_size,
                              hipStream_t stream) {
  const float* latent   = (const float*)d_in[0];
  const float* W_unpack = (const float*)d_in[1];
  const float* b_unpack = (const float*)d_in[2];
  const float* Wih0     = (const float*)d_in[3];
  const float* Whh0     = (const float*)d_in[4];
  const float* bih0     = (const float*)d_in[5];
  const float* bhh0     = (const float*)d_in[6];
  const float* Wih1     = (const float*)d_in[7];
  const float* Whh1     = (const float*)d_in[8];
  const float* bih1     = (const float*)d_in[9];
  const float* bhh1     = (const float*)d_in[10];
  const float* W_angle  = (const float*)d_in[11];
  const float* b_angle  = (const float*)d_in[12];
  float* out = (float*)d_out;

  const size_t HC = (size_t)BATCH * RNN;  // 2M floats
  float* ws    = (float*)d_ws;
  float* h0a   = ws;
  float* h1a   = h0a + HC;
  float* c0    = h1a + HC;
  float* c1    = c0 + HC;
  float* angle = c1 + HC;                 // BATCH floats
  float* h0b   = angle + BATCH;
  float* h1b   = h0b + HC;
  float* x     = h1b + HC;
  float* base  = x + (size_t)BATCH * CODE;

  // zero the step-0-read state: h0a, h1a, c0, c1, angle (contiguous)
  hipMemsetAsync(ws, 0, (4 * HC + BATCH) * sizeof(float), stream);

  base_kernel<<<BATCH, 256, 0, stream>>>(latent, W_unpack, b_unpack, base);

  dim3 ggrid(16, 32);
  for (int s = 0; s < NSEG; ++s) {
    const int p = s & 1;
    float* h0p = p ? h0b : h0a; float* h0n = p ? h0a : h0b;
    float* h1p = p ? h1b : h1a; float* h1n = p ? h1a : h1b;
    x_kernel<<<(BATCH * CODE) / 256, 256, 0, stream>>>(base, angle, W_unpack, x);
    gemm_lstm<<<ggrid, 256, 0, stream>>>(x, Wih0, h0p, Whh0, bih0, bhh0, c0, h0n);
    gemm_lstm<<<ggrid, 256, 0, stream>>>(h0n, Wih1, h1p, Whh1, bih1, bhh1, c1, h1n);
    head_kernel<<<BATCH, 64, 0, stream>>>(h1n, W_angle, b_angle, angle, out, s);
  }
}